// Round 1
// baseline (656.248 us; speedup 1.0000x reference)
//
#include <hip/hip_runtime.h>
#include <math.h>

#define B  32
#define A  512
#define EH 256
#define DH 384
#define HW 4096   // 64*64

// ---------------------------------------------------------------------------
// k1: dec_proj[b][a] = sum_k dec_h[b][k] * W_dec[a][k] + b_dec[a]
// one wave per (b,a); lanes parallel over k (coalesced on both operands)
// ---------------------------------------------------------------------------
__global__ void k_decproj(const float* __restrict__ dec_h,
                          const float* __restrict__ W_dec,
                          const float* __restrict__ b_dec,
                          float* __restrict__ dec_proj) {
    int wave = (blockIdx.x * blockDim.x + threadIdx.x) >> 6;
    int lane = threadIdx.x & 63;
    if (wave >= B * A) return;
    int b = wave >> 9;      // wave / 512
    int a = wave & 511;
    const float* dh = dec_h + b * DH;
    const float* wd = W_dec + a * DH;
    float acc = 0.f;
    for (int k = lane; k < DH; k += 64)
        acc += dh[k] * wd[k];
    #pragma unroll
    for (int s = 32; s > 0; s >>= 1)
        acc += __shfl_down(acc, s);
    if (lane == 0) dec_proj[wave] = acc + b_dec[a];
}

// ---------------------------------------------------------------------------
// k2: scores[b][p] = sum_a w_energy[a]*tanh(weo[b][a][p] + dec_proj[b][a]) + b_energy
// lane = pixel (contiguous -> coalesced); loop over a (stride HW floats)
// dec_proj row + w_energy staged in LDS (broadcast reads, conflict-free)
// ---------------------------------------------------------------------------
__global__ void k_scores(const float* __restrict__ weo,
                         const float* __restrict__ dec_proj,
                         const float* __restrict__ w_energy,
                         const float* __restrict__ b_energy,
                         float* __restrict__ scores) {
    __shared__ float s_dp[A];
    __shared__ float s_we[A];
    const int b = blockIdx.y;
    const int p = blockIdx.x * blockDim.x + threadIdx.x;
    for (int i = threadIdx.x; i < A; i += blockDim.x) {
        s_dp[i] = dec_proj[b * A + i];
        s_we[i] = w_energy[i];
    }
    __syncthreads();
    const float* base = weo + (size_t)b * A * HW + p;
    float acc = 0.f;
    #pragma unroll 4
    for (int a = 0; a < A; ++a) {
        float x = base[(size_t)a * HW];
        acc += s_we[a] * tanhf(x + s_dp[a]);
    }
    scores[b * HW + p] = acc + b_energy[0];
}

// ---------------------------------------------------------------------------
// k3: softmax over the 4096 pixels of one batch; one block per batch
// ---------------------------------------------------------------------------
__global__ void k_softmax(const float* __restrict__ scores,
                          float* __restrict__ alphas) {
    __shared__ float red[256];
    const int b = blockIdx.x;
    const float* s = scores + b * HW;
    float vals[16];
    float m = -INFINITY;
    #pragma unroll
    for (int i = 0; i < 16; ++i) {
        vals[i] = s[threadIdx.x + i * 256];
        m = fmaxf(m, vals[i]);
    }
    red[threadIdx.x] = m; __syncthreads();
    for (int s2 = 128; s2 > 0; s2 >>= 1) {
        if (threadIdx.x < s2)
            red[threadIdx.x] = fmaxf(red[threadIdx.x], red[threadIdx.x + s2]);
        __syncthreads();
    }
    m = red[0]; __syncthreads();
    float sum = 0.f;
    #pragma unroll
    for (int i = 0; i < 16; ++i) { vals[i] = expf(vals[i] - m); sum += vals[i]; }
    red[threadIdx.x] = sum; __syncthreads();
    for (int s2 = 128; s2 > 0; s2 >>= 1) {
        if (threadIdx.x < s2)
            red[threadIdx.x] += red[threadIdx.x + s2];
        __syncthreads();
    }
    const float inv = 1.f / red[0];
    float* out = alphas + b * HW;
    #pragma unroll
    for (int i = 0; i < 16; ++i)
        out[threadIdx.x + i * 256] = vals[i] * inv;
}

// ---------------------------------------------------------------------------
// k4: context[b][c] = sum_p enc[b][c][p] * alphas[b][p]
// one wave per (b,c); float4 loads over the contiguous 16 KB channel row
// ---------------------------------------------------------------------------
__global__ void k_context(const float* __restrict__ enc,
                          const float* __restrict__ alphas,
                          float* __restrict__ context) {
    const int b = blockIdx.y;
    const int wave = threadIdx.x >> 6;
    const int lane = threadIdx.x & 63;
    const int c = blockIdx.x * 4 + wave;
    const float4* e4 = (const float4*)(enc + ((size_t)b * EH + c) * HW);
    const float4* a4 = (const float4*)(alphas + (size_t)b * HW);
    float acc = 0.f;
    #pragma unroll
    for (int it = 0; it < 16; ++it) {
        float4 v  = e4[it * 64 + lane];
        float4 al = a4[it * 64 + lane];
        acc += v.x * al.x + v.y * al.y + v.z * al.z + v.w * al.w;
    }
    #pragma unroll
    for (int s = 32; s > 0; s >>= 1)
        acc += __shfl_down(acc, s);
    if (lane == 0) context[b * EH + c] = acc;
}

// ---------------------------------------------------------------------------
extern "C" void kernel_launch(void* const* d_in, const int* in_sizes, int n_in,
                              void* d_out, int out_size, void* d_ws, size_t ws_size,
                              hipStream_t stream) {
    const float* dec_h = (const float*)d_in[0];
    const float* weo   = (const float*)d_in[1];
    const float* enc   = (const float*)d_in[2];
    const float* W_dec = (const float*)d_in[3];
    const float* b_dec = (const float*)d_in[4];
    const float* w_en  = (const float*)d_in[5];
    const float* b_en  = (const float*)d_in[6];

    float* context = (float*)d_out;          // B*EH = 8192
    float* alphas  = context + B * EH;       // B*HW = 131072

    float* dec_proj = (float*)d_ws;          // B*A    = 16384 floats
    float* scores   = dec_proj + B * A;      // B*HW   = 131072 floats

    // k1: 16384 waves, 4 waves/block -> 4096 blocks
    k_decproj<<<dim3((B * A) / 4), 256, 0, stream>>>(dec_h, W_dec, b_dec, dec_proj);
    // k2: 16 pixel-chunks x 32 batches
    k_scores<<<dim3(HW / 256, B), 256, 0, stream>>>(weo, dec_proj, w_en, b_en, scores);
    // k3: one block per batch
    k_softmax<<<dim3(B), 256, 0, stream>>>(scores, alphas);
    // k4: 64 channel-chunks x 32 batches, 4 waves/block = 4 channels/block
    k_context<<<dim3(EH / 4, B), 256, 0, stream>>>(enc, alphas, context);
}

// Round 2
// 450.029 us; speedup vs baseline: 1.4582x; 1.4582x over previous
//
#include <hip/hip_runtime.h>
#include <math.h>

#define B  32
#define A  512
#define EH 256
#define DH 384
#define HW 4096   // 64*64
#define NCHUNK 8          // a-axis split for k2
#define ACH (A / NCHUNK)  // 64 a-values per chunk
#define P4 (HW / 4)       // 1024 float4 pixels per batch

// ---------------------------------------------------------------------------
// k1: dec_proj[b][a] = sum_k dec_h[b][k] * W_dec[a][k] + b_dec[a]
// one wave per (b,a); lanes parallel over k (coalesced on both operands)
// ---------------------------------------------------------------------------
__global__ void k_decproj(const float* __restrict__ dec_h,
                          const float* __restrict__ W_dec,
                          const float* __restrict__ b_dec,
                          float* __restrict__ dec_proj) {
    int wave = (blockIdx.x * blockDim.x + threadIdx.x) >> 6;
    int lane = threadIdx.x & 63;
    if (wave >= B * A) return;
    int b = wave >> 9;      // wave / 512
    int a = wave & 511;
    const float* dh = dec_h + b * DH;
    const float* wd = W_dec + a * DH;
    float acc = 0.f;
    for (int k = lane; k < DH; k += 64)
        acc += dh[k] * wd[k];
    #pragma unroll
    for (int s = 32; s > 0; s >>= 1)
        acc += __shfl_down(acc, s);
    if (lane == 0) dec_proj[wave] = acc + b_dec[a];
}

// ---------------------------------------------------------------------------
// k2: partial[b][chunk][p] = sum_{a in chunk} w_energy[a]*tanh(weo[b][a][p]+dp[b][a])
// thread = float4 of pixels; grid (4 pixel-chunks, 8 a-chunks, 32 batches)
// tanh(v) = 1 - 2/(exp2(v*2log2e)+1)  -> v_exp_f32 + v_rcp_f32, ~6 VALU/elem
// ---------------------------------------------------------------------------
__global__ void k_scores_part(const float* __restrict__ weo,
                              const float* __restrict__ dec_proj,
                              const float* __restrict__ w_energy,
                              float* __restrict__ partial) {
    __shared__ float s_dp[ACH];   // dec_proj * 2log2e (pre-scaled for exp2 arg)
    __shared__ float s_we[ACH];
    const int b  = blockIdx.z;
    const int a0 = blockIdx.y * ACH;
    const int p4 = blockIdx.x * blockDim.x + threadIdx.x;   // [0, 1024)
    const float C = 2.8853900817779268f;                    // 2*log2(e)

    if (threadIdx.x < ACH) {
        s_dp[threadIdx.x] = dec_proj[b * A + a0 + threadIdx.x] * C;
        s_we[threadIdx.x] = w_energy[a0 + threadIdx.x];
    }
    __syncthreads();

    const float4* w4 = (const float4*)(weo + ((size_t)b * A + a0) * HW);
    float4 acc = make_float4(0.f, 0.f, 0.f, 0.f);
    #pragma unroll 8
    for (int a = 0; a < ACH; ++a) {
        float4 x = w4[(size_t)a * P4 + p4];
        float dp = s_dp[a];
        float we = s_we[a];
        float rx = __builtin_amdgcn_rcpf(__builtin_amdgcn_exp2f(fmaf(x.x, C, dp)) + 1.f);
        float ry = __builtin_amdgcn_rcpf(__builtin_amdgcn_exp2f(fmaf(x.y, C, dp)) + 1.f);
        float rz = __builtin_amdgcn_rcpf(__builtin_amdgcn_exp2f(fmaf(x.z, C, dp)) + 1.f);
        float rw = __builtin_amdgcn_rcpf(__builtin_amdgcn_exp2f(fmaf(x.w, C, dp)) + 1.f);
        acc.x = fmaf(we, fmaf(-2.f, rx, 1.f), acc.x);
        acc.y = fmaf(we, fmaf(-2.f, ry, 1.f), acc.y);
        acc.z = fmaf(we, fmaf(-2.f, rz, 1.f), acc.z);
        acc.w = fmaf(we, fmaf(-2.f, rw, 1.f), acc.w);
    }
    float4* out4 = (float4*)partial;
    out4[((size_t)(b * NCHUNK + blockIdx.y)) * P4 + p4] = acc;
}

// ---------------------------------------------------------------------------
// k3: scores[b][p] = sum_chunk partial[b][chunk][p] + b_energy; softmax -> alphas
// one block per batch; partials are L2-resident (8 MB total)
// ---------------------------------------------------------------------------
__global__ void k_softmax(const float* __restrict__ partial,
                          const float* __restrict__ b_energy,
                          float* __restrict__ alphas) {
    __shared__ float red[256];
    const int b = blockIdx.x;
    const float be = b_energy[0];
    float vals[16];
    float m = -INFINITY;
    #pragma unroll
    for (int i = 0; i < 16; ++i) {
        int p = threadIdx.x + i * 256;
        float s = be;
        #pragma unroll
        for (int c = 0; c < NCHUNK; ++c)
            s += partial[((size_t)(b * NCHUNK + c) << 12) + p];
        vals[i] = s;
        m = fmaxf(m, s);
    }
    red[threadIdx.x] = m; __syncthreads();
    for (int s2 = 128; s2 > 0; s2 >>= 1) {
        if (threadIdx.x < s2)
            red[threadIdx.x] = fmaxf(red[threadIdx.x], red[threadIdx.x + s2]);
        __syncthreads();
    }
    m = red[0]; __syncthreads();
    float sum = 0.f;
    #pragma unroll
    for (int i = 0; i < 16; ++i) { vals[i] = __expf(vals[i] - m); sum += vals[i]; }
    red[threadIdx.x] = sum; __syncthreads();
    for (int s2 = 128; s2 > 0; s2 >>= 1) {
        if (threadIdx.x < s2)
            red[threadIdx.x] += red[threadIdx.x + s2];
        __syncthreads();
    }
    const float inv = 1.f / red[0];
    float* out = alphas + b * HW;
    #pragma unroll
    for (int i = 0; i < 16; ++i)
        out[threadIdx.x + i * 256] = vals[i] * inv;
}

// ---------------------------------------------------------------------------
// k4: context[b][c] = sum_p enc[b][c][p] * alphas[b][p]
// one wave per (b,c); float4 loads over the contiguous 16 KB channel row
// ---------------------------------------------------------------------------
__global__ void k_context(const float* __restrict__ enc,
                          const float* __restrict__ alphas,
                          float* __restrict__ context) {
    const int b = blockIdx.y;
    const int wave = threadIdx.x >> 6;
    const int lane = threadIdx.x & 63;
    const int c = blockIdx.x * 4 + wave;
    const float4* e4 = (const float4*)(enc + ((size_t)b * EH + c) * HW);
    const float4* a4 = (const float4*)(alphas + (size_t)b * HW);
    float acc = 0.f;
    #pragma unroll
    for (int it = 0; it < 16; ++it) {
        float4 v  = e4[it * 64 + lane];
        float4 al = a4[it * 64 + lane];
        acc += v.x * al.x + v.y * al.y + v.z * al.z + v.w * al.w;
    }
    #pragma unroll
    for (int s = 32; s > 0; s >>= 1)
        acc += __shfl_down(acc, s);
    if (lane == 0) context[b * EH + c] = acc;
}

// ---------------------------------------------------------------------------
extern "C" void kernel_launch(void* const* d_in, const int* in_sizes, int n_in,
                              void* d_out, int out_size, void* d_ws, size_t ws_size,
                              hipStream_t stream) {
    const float* dec_h = (const float*)d_in[0];
    const float* weo   = (const float*)d_in[1];
    const float* enc   = (const float*)d_in[2];
    const float* W_dec = (const float*)d_in[3];
    const float* b_dec = (const float*)d_in[4];
    const float* w_en  = (const float*)d_in[5];
    const float* b_en  = (const float*)d_in[6];

    float* context = (float*)d_out;          // B*EH = 8192
    float* alphas  = context + B * EH;       // B*HW = 131072

    float* dec_proj = (float*)d_ws;                 // B*A = 16384 floats (64 KB)
    float* partial  = dec_proj + B * A;             // B*NCHUNK*HW = 1 M floats (4 MB)

    // k1: 16384 waves, 4 waves/block -> 4096 blocks
    k_decproj<<<dim3((B * A) / 4), 256, 0, stream>>>(dec_h, W_dec, b_dec, dec_proj);
    // k2: (pixel-chunks, a-chunks, batches) = (4, 8, 32) = 1024 blocks
    k_scores_part<<<dim3(P4 / 256, NCHUNK, B), 256, 0, stream>>>(weo, dec_proj, w_en, partial);
    // k3: one block per batch
    k_softmax<<<dim3(B), 256, 0, stream>>>(partial, b_en, alphas);
    // k4: 64 channel-chunks x 32 batches, 4 waves/block = 4 channels/block
    k_context<<<dim3(EH / 4, B), 256, 0, stream>>>(enc, alphas, context);
}